// Round 2
// baseline (615.440 us; speedup 1.0000x reference)
//
#include <hip/hip_runtime.h>
#include <stdint.h>

typedef __attribute__((ext_vector_type(8))) short bf16x8;   // 8 bf16 = 4 VGPRs (MFMA operand)
typedef __attribute__((ext_vector_type(4))) float f32x4;    // MFMA acc
typedef __attribute__((ext_vector_type(4))) unsigned short u16x4;
typedef __attribute__((ext_vector_type(4))) float float4v;

#define F 256

static __device__ __forceinline__ float bf2f(unsigned short h) {
  union { uint32_t u; float f; } x; x.u = ((uint32_t)h) << 16; return x.f;
}
static __device__ __forceinline__ unsigned short f2bf(float f) {
  union { float f; uint32_t u; } x; x.f = f;
  uint32_t u = x.u;
  return (unsigned short)((u + 0x7FFFu + ((u >> 16) & 1u)) >> 16);  // RNE, matches np/jax cast
}

// ---- CSR build ----
__global__ void hist_kernel(const int* __restrict__ dst, int* __restrict__ counts, int E) {
  int i = blockIdx.x * blockDim.x + threadIdx.x;
  if (i < E) atomicAdd(&counts[dst[i]], 1);
}

__global__ void scan_kernel(const int* __restrict__ counts, int* __restrict__ row_ptr, int n) {
  __shared__ int sums[1024];
  const int tid = threadIdx.x;
  const int chunk = (n + 1023) / 1024;
  const int s = tid * chunk;
  const int e = min(s + chunk, n);
  int sum = 0;
  for (int i = s; i < e; ++i) sum += counts[i];
  sums[tid] = sum;
  __syncthreads();
  for (int off = 1; off < 1024; off <<= 1) {
    int t = (tid >= off) ? sums[tid - off] : 0;
    __syncthreads();
    sums[tid] += t;
    __syncthreads();
  }
  int run = sums[tid] - sum;  // exclusive prefix of this chunk
  for (int i = s; i < e; ++i) { row_ptr[i] = run; run += counts[i]; }
  if (tid == 1023) row_ptr[n] = sums[1023];
}

__global__ void finalize_kernel(const int* __restrict__ counts, const int* __restrict__ row_ptr,
                                int* __restrict__ cursor, float* __restrict__ dis, int n) {
  int i = blockIdx.x * blockDim.x + threadIdx.x;
  if (i < n) {
    cursor[i] = row_ptr[i];
    dis[i] = rsqrtf((float)(counts[i] + 1));  // deg includes self-loop, always >0
  }
}

__global__ void fill_kernel(const int* __restrict__ src, const int* __restrict__ dst,
                            int* __restrict__ cursor, int* __restrict__ col, int E) {
  int i = blockIdx.x * blockDim.x + threadIdx.x;
  if (i < E) {
    int p = atomicAdd(&cursor[dst[i]], 1);
    col[p] = src[i];
  }
}

// WT[n][k] = bf16(W[k][n])  (fp32 in, bf16 out; tiny, L2-resident)
__global__ void transpose_kernel(const float* __restrict__ W, unsigned short* __restrict__ WT) {
  int i = blockIdx.x * 256 + threadIdx.x;  // i = n*256 + k
  WT[i] = f2bf(W[(i & 255) * 256 + (i >> 8)]);
}

// ---- GEMM: G[m][n] = bf16( dis[m] * sum_k A[m][k]*BT[n][k] ) ----
// block tile 128x128, 4 waves 2x2, each wave 64x64 = 4x4 frags of 16x16x32 MFMA.
// A is fp32 (layer 1: x) or bf16 (layer 2: t), selected by A_FP32.
template <int A_FP32>
__global__ __launch_bounds__(256) void gemm_kernel(
    const void* __restrict__ Av,
    const unsigned short* __restrict__ BT,  // [256][256] bf16 (W transposed)
    const float* __restrict__ dis,
    unsigned short* __restrict__ G, int M)
{
  const int tid = threadIdx.x;
  const int w = tid >> 6;
  const int l = tid & 63;
  const int row0 = blockIdx.x * 128 + (w >> 1) * 64;
  const int col0 = blockIdx.y * 128 + (w & 1) * 64;
  const int lr = l & 15;          // frag row (A) / col (B)
  const int lk = (l >> 4) * 8;    // frag k offset

  f32x4 acc[4][4] = {};
  for (int kk = 0; kk < F; kk += 32) {
    bf16x8 a[4], b[4];
#pragma unroll
    for (int i = 0; i < 4; ++i) {
      int r = row0 + i * 16 + lr;
      r = r < M ? r : M - 1;  // clamp tail rows (stores are guarded)
      if constexpr (A_FP32) {
        const float* A = (const float*)Av;
        const float4v* pA = reinterpret_cast<const float4v*>(A + (size_t)r * F + kk + lk);
        float4v u0 = pA[0], u1 = pA[1];
        bf16x8 af;
        af[0] = (short)f2bf(u0[0]); af[1] = (short)f2bf(u0[1]);
        af[2] = (short)f2bf(u0[2]); af[3] = (short)f2bf(u0[3]);
        af[4] = (short)f2bf(u1[0]); af[5] = (short)f2bf(u1[1]);
        af[6] = (short)f2bf(u1[2]); af[7] = (short)f2bf(u1[3]);
        a[i] = af;
      } else {
        const unsigned short* A = (const unsigned short*)Av;
        a[i] = *reinterpret_cast<const bf16x8*>(A + (size_t)r * F + kk + lk);
      }
      b[i] = *reinterpret_cast<const bf16x8*>(BT + (size_t)(col0 + i * 16 + lr) * F + kk + lk);
    }
#pragma unroll
    for (int i = 0; i < 4; ++i)
#pragma unroll
      for (int j = 0; j < 4; ++j)
        acc[i][j] = __builtin_amdgcn_mfma_f32_16x16x32_bf16(a[i], b[j], acc[i][j], 0, 0, 0);
  }
  // C/D layout: col = lane&15, row = (lane>>4)*4 + reg
  const int orow = (l >> 4) * 4;
  const int ocol = l & 15;
#pragma unroll
  for (int i = 0; i < 4; ++i) {
#pragma unroll
    for (int r = 0; r < 4; ++r) {
      int row = row0 + i * 16 + orow + r;
      if (row < M) {
        float d = dis[row];
#pragma unroll
        for (int j = 0; j < 4; ++j)
          G[(size_t)row * F + col0 + j * 16 + ocol] = f2bf(acc[i][j][r] * d);
      }
    }
  }
}

// ---- aggregation: out[n] = act( dis[n]*(sum_{e in row n} G[col[e]] + G[n]) + bias ) ----
// 1 wave per node, 4 features per lane (64*4 = 256), fp32 accumulate.
// LAST=0: write bf16 (feeds next GEMM).  LAST=1: apply PReLU, write fp32 to d_out.
template <int LAST>
__global__ __launch_bounds__(256) void aggregate_kernel(
    const unsigned short* __restrict__ Gm, const float* __restrict__ dis,
    const int* __restrict__ row_ptr, const int* __restrict__ col,
    const float* __restrict__ bias, const float* __restrict__ pa,
    void* __restrict__ outv, int N)
{
  const int w = threadIdx.x >> 6;
  const int l = threadIdx.x & 63;
  const int n = blockIdx.x * 4 + w;
  if (n >= N) return;
  const int f = l * 4;
  float a0, a1, a2, a3;
  {
    u16x4 v = *reinterpret_cast<const u16x4*>(Gm + (size_t)n * F + f);  // self-loop term
    a0 = bf2f(v[0]); a1 = bf2f(v[1]); a2 = bf2f(v[2]); a3 = bf2f(v[3]);
  }
  const int s = row_ptr[n], e = row_ptr[n + 1];
  int i = s;
  for (; i + 2 <= e; i += 2) {
    int c0 = col[i], c1 = col[i + 1];
    u16x4 v0 = *reinterpret_cast<const u16x4*>(Gm + (size_t)c0 * F + f);
    u16x4 v1 = *reinterpret_cast<const u16x4*>(Gm + (size_t)c1 * F + f);
    a0 += bf2f(v0[0]) + bf2f(v1[0]);
    a1 += bf2f(v0[1]) + bf2f(v1[1]);
    a2 += bf2f(v0[2]) + bf2f(v1[2]);
    a3 += bf2f(v0[3]) + bf2f(v1[3]);
  }
  if (i < e) {
    int c0 = col[i];
    u16x4 v0 = *reinterpret_cast<const u16x4*>(Gm + (size_t)c0 * F + f);
    a0 += bf2f(v0[0]); a1 += bf2f(v0[1]); a2 += bf2f(v0[2]); a3 += bf2f(v0[3]);
  }
  const float d = dis[n];
  float r0 = a0 * d + bias[f + 0];
  float r1 = a1 * d + bias[f + 1];
  float r2 = a2 * d + bias[f + 2];
  float r3 = a3 * d + bias[f + 3];
  if constexpr (LAST) {
    if (r0 < 0.f) r0 *= pa[f + 0];
    if (r1 < 0.f) r1 *= pa[f + 1];
    if (r2 < 0.f) r2 *= pa[f + 2];
    if (r3 < 0.f) r3 *= pa[f + 3];
    float4v o; o[0] = r0; o[1] = r1; o[2] = r2; o[3] = r3;
    *reinterpret_cast<float4v*>((float*)outv + (size_t)n * F + f) = o;
  } else {
    u16x4 o;
    o[0] = f2bf(r0); o[1] = f2bf(r1); o[2] = f2bf(r2); o[3] = f2bf(r3);
    *reinterpret_cast<u16x4*>((unsigned short*)outv + (size_t)n * F + f) = o;
  }
}

extern "C" void kernel_launch(void* const* d_in, const int* in_sizes, int n_in,
                              void* d_out, int out_size, void* d_ws, size_t ws_size,
                              hipStream_t stream) {
  const float* x  = (const float*)d_in[0];
  const int* ei   = (const int*)d_in[1];
  const float* W1 = (const float*)d_in[2];
  const float* b1 = (const float*)d_in[3];
  const float* W2 = (const float*)d_in[4];
  const float* b2 = (const float*)d_in[5];
  const float* pa = (const float*)d_in[6];

  const int N = in_sizes[0] / F;
  const int E = in_sizes[1] / 2;
  const int* src  = ei;
  const int* dstv = ei + E;

  // ws bump allocator (~59 MB total)
  char* p = (char*)d_ws;
  auto alloc = [&](size_t bytes) -> char* {
    char* r = p; p += (bytes + 255) & ~(size_t)255; return r;
  };
  int*   counts  = (int*)alloc(sizeof(int) * (size_t)N);
  int*   row_ptr = (int*)alloc(sizeof(int) * (size_t)(N + 1));
  int*   cursor  = (int*)alloc(sizeof(int) * (size_t)N);
  float* dis     = (float*)alloc(sizeof(float) * (size_t)N);
  int*   col     = (int*)alloc(sizeof(int) * (size_t)E);
  unsigned short* W1T = (unsigned short*)alloc(sizeof(short) * F * F);
  unsigned short* W2T = (unsigned short*)alloc(sizeof(short) * F * F);
  unsigned short* g   = (unsigned short*)alloc(sizeof(short) * (size_t)N * F);
  unsigned short* t   = (unsigned short*)alloc(sizeof(short) * (size_t)N * F);

  hipMemsetAsync(counts, 0, sizeof(int) * (size_t)N, stream);
  hist_kernel<<<(E + 255) / 256, 256, 0, stream>>>(dstv, counts, E);
  scan_kernel<<<1, 1024, 0, stream>>>(counts, row_ptr, N);
  finalize_kernel<<<(N + 255) / 256, 256, 0, stream>>>(counts, row_ptr, cursor, dis, N);
  fill_kernel<<<(E + 255) / 256, 256, 0, stream>>>(src, dstv, cursor, col, E);
  transpose_kernel<<<F, 256, 0, stream>>>(W1, W1T);
  transpose_kernel<<<F, 256, 0, stream>>>(W2, W2T);

  dim3 ggrid((N + 127) / 128, F / 128);
  // layer 1: g = dis .* (bf16(x) @ bf16(W1))
  gemm_kernel<1><<<ggrid, 256, 0, stream>>>((const void*)x, W1T, dis, g, N);
  aggregate_kernel<0><<<(N + 3) / 4, 256, 0, stream>>>(g, dis, row_ptr, col, b1, pa, t, N);
  // layer 2 + bias + PReLU -> fp32 out
  gemm_kernel<0><<<ggrid, 256, 0, stream>>>((const void*)t, W2T, dis, g, N);
  aggregate_kernel<1><<<(N + 3) / 4, 256, 0, stream>>>(g, dis, row_ptr, col, b2, pa, d_out, N);
}

// Round 3
// 387.572 us; speedup vs baseline: 1.5879x; 1.5879x over previous
//
#include <hip/hip_runtime.h>
#include <stdint.h>

typedef __attribute__((ext_vector_type(8))) short bf16x8;   // 8 bf16 = 4 VGPRs (MFMA operand)
typedef __attribute__((ext_vector_type(4))) float f32x4;    // MFMA acc
typedef __attribute__((ext_vector_type(4))) unsigned short u16x4;
typedef __attribute__((ext_vector_type(4))) float float4v;

#define F 256
#define BKT_SHIFT 7               // 128 nodes per bucket
#define BKT_NODES 128
#define MAXNB 512                 // N <= 65536
#define CHUNK 4096                // edges per block in count/scatter

static __device__ __forceinline__ float bf2f(unsigned short h) {
  union { uint32_t u; float f; } x; x.u = ((uint32_t)h) << 16; return x.f;
}
static __device__ __forceinline__ unsigned short f2bf(float f) {
  union { float f; uint32_t u; } x; x.f = f;
  uint32_t u = x.u;
  return (unsigned short)((u + 0x7FFFu + ((u >> 16) & 1u)) >> 16);  // RNE, matches np/jax cast
}

// ---- P1: bucket histogram (LDS-privatized) ----
__global__ __launch_bounds__(256) void bcount_kernel(const int* __restrict__ dst,
                                                     int* __restrict__ bucket_cnt, int E, int NB) {
  __shared__ int cnt[MAXNB];
  const int tid = threadIdx.x;
  for (int t = tid; t < MAXNB; t += 256) cnt[t] = 0;
  __syncthreads();
  const int base = blockIdx.x * CHUNK;
#pragma unroll
  for (int j = 0; j < CHUNK / 256; ++j) {
    int i = base + j * 256 + tid;
    if (i < E) atomicAdd(&cnt[dst[i] >> BKT_SHIFT], 1);
  }
  __syncthreads();
  for (int t = tid; t < NB; t += 256)
    if (cnt[t]) atomicAdd(&bucket_cnt[t], cnt[t]);
}

// ---- P2: scan bucket counts (single block, 512 threads) ----
__global__ __launch_bounds__(512) void bscan_kernel(const int* __restrict__ bucket_cnt,
                                                    int* __restrict__ bucket_base,
                                                    int* __restrict__ gcursor,
                                                    int* __restrict__ row_ptr,
                                                    int NB, int N, int E) {
  __shared__ int s[512];
  const int tid = threadIdx.x;
  int v = (tid < NB) ? bucket_cnt[tid] : 0;
  s[tid] = v;
  __syncthreads();
  for (int off = 1; off < 512; off <<= 1) {
    int t = (tid >= off) ? s[tid - off] : 0;
    __syncthreads();
    s[tid] += t;
    __syncthreads();
  }
  int excl = s[tid] - v;
  if (tid < NB) { bucket_base[tid] = excl; gcursor[tid] = excl; }
  if (tid == NB - 1) bucket_base[NB] = excl + v;  // == E
  if (tid == 0) row_ptr[N] = E;
}

// ---- P3: scatter edges into bucket-grouped pairs (src | dstlocal<<16) ----
__global__ __launch_bounds__(256) void scatter_kernel(const int* __restrict__ src,
                                                      const int* __restrict__ dst,
                                                      int* __restrict__ gcursor,
                                                      uint32_t* __restrict__ pairs, int E, int NB) {
  __shared__ int cnt[MAXNB];
  __shared__ int gbase[MAXNB];
  const int tid = threadIdx.x;
  for (int t = tid; t < MAXNB; t += 256) cnt[t] = 0;
  __syncthreads();
  const int base = blockIdx.x * CHUNK;
  uint32_t val[CHUNK / 256];
  int bk[CHUNK / 256], pos[CHUNK / 256];
#pragma unroll
  for (int j = 0; j < CHUNK / 256; ++j) {
    int i = base + j * 256 + tid;
    if (i < E) {
      int s = src[i], d = dst[i];
      bk[j] = d >> BKT_SHIFT;
      val[j] = (uint32_t)s | ((uint32_t)(d & (BKT_NODES - 1)) << 16);
      pos[j] = atomicAdd(&cnt[bk[j]], 1);
    } else bk[j] = -1;
  }
  __syncthreads();
  for (int t = tid; t < NB; t += 256)
    gbase[t] = cnt[t] ? atomicAdd(&gcursor[t], cnt[t]) : 0;
  __syncthreads();
#pragma unroll
  for (int j = 0; j < CHUNK / 256; ++j)
    if (bk[j] >= 0) pairs[(size_t)gbase[bk[j]] + pos[j]] = val[j];
}

// ---- P4: per-bucket local counting sort -> row_ptr, dis, col (u16) ----
__global__ __launch_bounds__(256) void build_kernel(const uint32_t* __restrict__ pairs,
                                                    const int* __restrict__ bucket_base,
                                                    int* __restrict__ row_ptr,
                                                    float* __restrict__ dis,
                                                    unsigned short* __restrict__ col, int N) {
  __shared__ int hcnt[BKT_NODES], hcur[BKT_NODES];
  __shared__ int s[256];
  const int b = blockIdx.x;
  const int tid = threadIdx.x;
  const int e0 = bucket_base[b], e1 = bucket_base[b + 1];
  if (tid < BKT_NODES) hcnt[tid] = 0;
  __syncthreads();
  for (int i = e0 + tid; i < e1; i += 256) atomicAdd(&hcnt[pairs[i] >> 16], 1);
  __syncthreads();
  int v = (tid < BKT_NODES) ? hcnt[tid] : 0;
  s[tid] = v;
  __syncthreads();
  for (int off = 1; off < BKT_NODES; off <<= 1) {
    int t = (tid >= off) ? s[tid - off] : 0;
    __syncthreads();
    s[tid] += t;
    __syncthreads();
  }
  if (tid < BKT_NODES) {
    int excl = s[tid] - v;
    hcur[tid] = excl;
    int node = b * BKT_NODES + tid;
    if (node < N) {
      row_ptr[node] = e0 + excl;
      dis[node] = rsqrtf((float)(v + 1));  // deg incl self-loop
    }
  }
  __syncthreads();
  for (int i = e0 + tid; i < e1; i += 256) {
    uint32_t pv = pairs[i];
    int p = atomicAdd(&hcur[pv >> 16], 1);
    col[(size_t)e0 + p] = (unsigned short)(pv & 0xFFFFu);
  }
}

// WT[n][k] = bf16(W[k][n])  (fp32 in, bf16 out; tiny, L2-resident)
__global__ void transpose_kernel(const float* __restrict__ W, unsigned short* __restrict__ WT) {
  int i = blockIdx.x * 256 + threadIdx.x;  // i = n*256 + k
  WT[i] = f2bf(W[(i & 255) * 256 + (i >> 8)]);
}

// ---- GEMM: G[m][n] = bf16( dis[m] * sum_k A[m][k]*BT[n][k] ) ----
template <int A_FP32>
__global__ __launch_bounds__(256) void gemm_kernel(
    const void* __restrict__ Av,
    const unsigned short* __restrict__ BT,  // [256][256] bf16 (W transposed)
    const float* __restrict__ dis,
    unsigned short* __restrict__ G, int M)
{
  const int tid = threadIdx.x;
  const int w = tid >> 6;
  const int l = tid & 63;
  const int row0 = blockIdx.x * 128 + (w >> 1) * 64;
  const int col0 = blockIdx.y * 128 + (w & 1) * 64;
  const int lr = l & 15;
  const int lk = (l >> 4) * 8;

  f32x4 acc[4][4] = {};
  for (int kk = 0; kk < F; kk += 32) {
    bf16x8 a[4], b[4];
#pragma unroll
    for (int i = 0; i < 4; ++i) {
      int r = row0 + i * 16 + lr;
      r = r < M ? r : M - 1;  // clamp tail rows (stores guarded)
      if constexpr (A_FP32) {
        const float* A = (const float*)Av;
        const float4v* pA = reinterpret_cast<const float4v*>(A + (size_t)r * F + kk + lk);
        float4v u0 = pA[0], u1 = pA[1];
        bf16x8 af;
        af[0] = (short)f2bf(u0[0]); af[1] = (short)f2bf(u0[1]);
        af[2] = (short)f2bf(u0[2]); af[3] = (short)f2bf(u0[3]);
        af[4] = (short)f2bf(u1[0]); af[5] = (short)f2bf(u1[1]);
        af[6] = (short)f2bf(u1[2]); af[7] = (short)f2bf(u1[3]);
        a[i] = af;
      } else {
        const unsigned short* A = (const unsigned short*)Av;
        a[i] = *reinterpret_cast<const bf16x8*>(A + (size_t)r * F + kk + lk);
      }
      b[i] = *reinterpret_cast<const bf16x8*>(BT + (size_t)(col0 + i * 16 + lr) * F + kk + lk);
    }
#pragma unroll
    for (int i = 0; i < 4; ++i)
#pragma unroll
      for (int j = 0; j < 4; ++j)
        acc[i][j] = __builtin_amdgcn_mfma_f32_16x16x32_bf16(a[i], b[j], acc[i][j], 0, 0, 0);
  }
  const int orow = (l >> 4) * 4;
  const int ocol = l & 15;
#pragma unroll
  for (int i = 0; i < 4; ++i) {
#pragma unroll
    for (int r = 0; r < 4; ++r) {
      int row = row0 + i * 16 + orow + r;
      if (row < M) {
        float d = dis[row];
#pragma unroll
        for (int j = 0; j < 4; ++j)
          G[(size_t)row * F + col0 + j * 16 + ocol] = f2bf(acc[i][j][r] * d);
      }
    }
  }
}

// ---- aggregation: out[n] = act( dis[n]*(sum_{e in row n} G[col[e]] + G[n]) + bias ) ----
template <int LAST>
__global__ __launch_bounds__(256) void aggregate_kernel(
    const unsigned short* __restrict__ Gm, const float* __restrict__ dis,
    const int* __restrict__ row_ptr, const unsigned short* __restrict__ col,
    const float* __restrict__ bias, const float* __restrict__ pa,
    void* __restrict__ outv, int N)
{
  const int w = threadIdx.x >> 6;
  const int l = threadIdx.x & 63;
  const int n = blockIdx.x * 4 + w;
  if (n >= N) return;
  const int f = l * 4;
  float a0, a1, a2, a3;
  {
    u16x4 v = *reinterpret_cast<const u16x4*>(Gm + (size_t)n * F + f);  // self-loop term
    a0 = bf2f(v[0]); a1 = bf2f(v[1]); a2 = bf2f(v[2]); a3 = bf2f(v[3]);
  }
  const int s = row_ptr[n], e = row_ptr[n + 1];
  int i = s;
  for (; i + 2 <= e; i += 2) {
    int c0 = col[i], c1 = col[i + 1];
    u16x4 v0 = *reinterpret_cast<const u16x4*>(Gm + (size_t)c0 * F + f);
    u16x4 v1 = *reinterpret_cast<const u16x4*>(Gm + (size_t)c1 * F + f);
    a0 += bf2f(v0[0]) + bf2f(v1[0]);
    a1 += bf2f(v0[1]) + bf2f(v1[1]);
    a2 += bf2f(v0[2]) + bf2f(v1[2]);
    a3 += bf2f(v0[3]) + bf2f(v1[3]);
  }
  if (i < e) {
    int c0 = col[i];
    u16x4 v0 = *reinterpret_cast<const u16x4*>(Gm + (size_t)c0 * F + f);
    a0 += bf2f(v0[0]); a1 += bf2f(v0[1]); a2 += bf2f(v0[2]); a3 += bf2f(v0[3]);
  }
  const float d = dis[n];
  float r0 = a0 * d + bias[f + 0];
  float r1 = a1 * d + bias[f + 1];
  float r2 = a2 * d + bias[f + 2];
  float r3 = a3 * d + bias[f + 3];
  if constexpr (LAST) {
    if (r0 < 0.f) r0 *= pa[f + 0];
    if (r1 < 0.f) r1 *= pa[f + 1];
    if (r2 < 0.f) r2 *= pa[f + 2];
    if (r3 < 0.f) r3 *= pa[f + 3];
    float4v o; o[0] = r0; o[1] = r1; o[2] = r2; o[3] = r3;
    *reinterpret_cast<float4v*>((float*)outv + (size_t)n * F + f) = o;
  } else {
    u16x4 o;
    o[0] = f2bf(r0); o[1] = f2bf(r1); o[2] = f2bf(r2); o[3] = f2bf(r3);
    *reinterpret_cast<u16x4*>((unsigned short*)outv + (size_t)n * F + f) = o;
  }
}

extern "C" void kernel_launch(void* const* d_in, const int* in_sizes, int n_in,
                              void* d_out, int out_size, void* d_ws, size_t ws_size,
                              hipStream_t stream) {
  const float* x  = (const float*)d_in[0];
  const int* ei   = (const int*)d_in[1];
  const float* W1 = (const float*)d_in[2];
  const float* b1 = (const float*)d_in[3];
  const float* W2 = (const float*)d_in[4];
  const float* b2 = (const float*)d_in[5];
  const float* pa = (const float*)d_in[6];

  const int N = in_sizes[0] / F;
  const int E = in_sizes[1] / 2;
  const int NB = (N + BKT_NODES - 1) >> BKT_SHIFT;   // 391 for N=50000
  const int* src  = ei;
  const int* dstv = ei + E;

  // ws bump allocator
  char* p = (char*)d_ws;
  auto alloc = [&](size_t bytes) -> char* {
    char* r = p; p += (bytes + 255) & ~(size_t)255; return r;
  };
  int*   bucket_cnt  = (int*)alloc(sizeof(int) * MAXNB);
  int*   bucket_base = (int*)alloc(sizeof(int) * (MAXNB + 1));
  int*   gcursor     = (int*)alloc(sizeof(int) * MAXNB);
  int*   row_ptr     = (int*)alloc(sizeof(int) * (size_t)(N + 1));
  float* dis         = (float*)alloc(sizeof(float) * (size_t)N);
  unsigned short* col = (unsigned short*)alloc(sizeof(short) * (size_t)E);
  unsigned short* W1T = (unsigned short*)alloc(sizeof(short) * F * F);
  unsigned short* W2T = (unsigned short*)alloc(sizeof(short) * F * F);
  unsigned short* g   = (unsigned short*)alloc(sizeof(short) * (size_t)N * F);
  unsigned short* t   = (unsigned short*)alloc(sizeof(short) * (size_t)N * F);
  uint32_t* pairs = (uint32_t*)t;  // alias: pairs dead before t is first written

  const int egrid = (E + CHUNK - 1) / CHUNK;
  hipMemsetAsync(bucket_cnt, 0, sizeof(int) * MAXNB, stream);
  bcount_kernel<<<egrid, 256, 0, stream>>>(dstv, bucket_cnt, E, NB);
  bscan_kernel<<<1, 512, 0, stream>>>(bucket_cnt, bucket_base, gcursor, row_ptr, NB, N, E);
  scatter_kernel<<<egrid, 256, 0, stream>>>(src, dstv, gcursor, pairs, E, NB);
  build_kernel<<<NB, 256, 0, stream>>>(pairs, bucket_base, row_ptr, dis, col, N);
  transpose_kernel<<<F, 256, 0, stream>>>(W1, W1T);
  transpose_kernel<<<F, 256, 0, stream>>>(W2, W2T);

  dim3 ggrid((N + 127) / 128, F / 128);
  // layer 1: g = dis .* (bf16(x) @ bf16(W1))
  gemm_kernel<1><<<ggrid, 256, 0, stream>>>((const void*)x, W1T, dis, g, N);
  aggregate_kernel<0><<<(N + 3) / 4, 256, 0, stream>>>(g, dis, row_ptr, col, b1, pa, t, N);
  // layer 2 + bias + PReLU -> fp32 out
  gemm_kernel<0><<<ggrid, 256, 0, stream>>>((const void*)t, W2T, dis, g, N);
  aggregate_kernel<1><<<(N + 3) / 4, 256, 0, stream>>>(g, dis, row_ptr, col, b2, pa, d_out, N);
}